// Round 18
// baseline (178.020 us; speedup 1.0000x reference)
//
#include <hip/hip_runtime.h>
#include <hip/hip_bf16.h>

typedef unsigned short u16t;
typedef __attribute__((ext_vector_type(8))) short bfrag;      // 8 bf16 bits
typedef __attribute__((ext_vector_type(4))) float f32x4;      // MFMA acc
typedef __attribute__((ext_vector_type(8))) unsigned short uh8;

__device__ __forceinline__ float bfu(u16t u) {
    union { unsigned int i; float f; } c;
    c.i = ((unsigned int)u) << 16;
    return c.f;
}
__device__ __forceinline__ u16t fbf(float f) {
    __hip_bfloat16 h = __float2bfloat16(f);
    return *reinterpret_cast<u16t*>(&h);
}
// HW packed f32x2 -> bf16x2 (single VALU op)
__device__ __forceinline__ unsigned int fbf2(float lo, float hi) {
    unsigned int r;
    asm("v_cvt_pk_bf16_f32 %0, %1, %2" : "=v"(r) : "v"(lo), "v"(hi));
    return r;
}
__device__ __forceinline__ float rcpf(float x) {
    float r;
    asm("v_rcp_f32 %0, %1" : "=v"(r) : "v"(x));
    return r;
}

// ---------------------------------------------------------------------------
// x [b][64c][64f][512t] fp32 -> three normalized bf16 copies in [b][f][t][64]
// ---------------------------------------------------------------------------
__global__ __launch_bounds__(256) void prep_x3_k(
    const float* __restrict__ x,
    const float* __restrict__ g0, const float* __restrict__ b0,
    const float* __restrict__ m0, const float* __restrict__ v0,
    const float* __restrict__ g1, const float* __restrict__ b1,
    const float* __restrict__ m1, const float* __restrict__ v1,
    const float* __restrict__ g2, const float* __restrict__ b2,
    const float* __restrict__ m2, const float* __restrict__ v2,
    u16t* __restrict__ xn0, u16t* __restrict__ xn1, u16t* __restrict__ xn2)
{
    constexpr int F = 64, T = 512;
    __shared__ u16t su[64][74];
    __shared__ float ssc[3][64], ssh[3][64];
    const int tid = threadIdx.x;
    const int t0 = blockIdx.x * 64;
    const int f = blockIdx.y, b = blockIdx.z;

    if (tid < 64) {
        int c = tid;
        float s;
        s = g0[c] * rsqrtf(v0[c] + 1e-5f); ssc[0][c] = s; ssh[0][c] = b0[c] - m0[c] * s;
        s = g1[c] * rsqrtf(v1[c] + 1e-5f); ssc[1][c] = s; ssh[1][c] = b1[c] - m1[c] * s;
        s = g2[c] * rsqrtf(v2[c] + 1e-5f); ssc[2][c] = s; ssh[2][c] = b2[c] - m2[c] * s;
    }
#pragma unroll
    for (int p = 0; p < 16; p++) {
        int i = tid + 256 * p;
        int c = i >> 6, t = i & 63;
        su[c][t] = fbf(x[(((long)b * 64 + c) * F + f) * T + t0 + t]);
    }
    __syncthreads();
#pragma unroll
    for (int p = 0; p < 2; p++) {
        int i = tid + 256 * p;
        int t = i >> 3, c8 = i & 7;
        float n0[8], n1[8], n2[8];
#pragma unroll
        for (int j = 0; j < 8; j++) {
            int c = c8 * 8 + j;
            float xv = bfu(su[c][t]);
            float a0 = fmaf(xv, ssc[0][c], ssh[0][c]);
            float a1 = fmaf(xv, ssc[1][c], ssh[1][c]);
            float a2 = fmaf(xv, ssc[2][c], ssh[2][c]);
            n0[j] = fmaxf(a0, 0.01f * a0);
            n1[j] = fmaxf(a1, 0.01f * a1);
            n2[j] = fmaxf(a2, 0.01f * a2);
        }
        union { uh8 h; unsigned int w[4]; } u0, u1, u2;
#pragma unroll
        for (int j4 = 0; j4 < 4; j4++) {
            u0.w[j4] = fbf2(n0[j4 * 2], n0[j4 * 2 + 1]);
            u1.w[j4] = fbf2(n1[j4 * 2], n1[j4 * 2 + 1]);
            u2.w[j4] = fbf2(n2[j4 * 2], n2[j4 * 2 + 1]);
        }
        long gi = (((long)b * F + f) * T + t0 + t) * 64 + c8 * 8;
        *(uh8*)&xn0[gi] = u0.h;
        *(uh8*)&xn1[gi] = u1.h;
        *(uh8*)&xn2[gi] = u2.h;
    }
}

// ---------------------------------------------------------------------------
// Pack weights fp32 -> bf16 fragments (layout proven round 10).
// ---------------------------------------------------------------------------
__global__ __launch_bounds__(256) void prep_w_k(
    const float* __restrict__ w0, const float* __restrict__ w1,
    const float* __restrict__ w2, const float* __restrict__ ow,
    const float* __restrict__ sw, const float* __restrict__ qw,
    u16t* __restrict__ wp)
{
    int idx = blockIdx.x * 256 + threadIdx.x;
    if (idx >= 144384) return;
    if (idx < 119808) {
        int C_IN, C_OUT, e;
        const float* src;
        if (idx < 18432)      { C_IN = 64;  C_OUT = 32; src = w0; e = idx; }
        else if (idx < 46080) { C_IN = 96;  C_OUT = 32; src = w1; e = idx - 18432; }
        else                  { C_IN = 128; C_OUT = 64; src = w2; e = idx - 46080; }
        int NCOT = C_OUT / 16;
        int j  = e & 7;
        int l  = (e >> 3) & 63;
        int r  = e >> 9;
        int ct = r % NCOT;
        int r2 = r / NCOT;
        int kk = r2 % 9;
        int cb = r2 / 9;
        int co  = ct * 16 + (l & 15);
        int kin = cb * 32 + (l >> 4) * 8 + j;
        int kh = kk / 3, kw = kk % 3;
        wp[idx] = fbf(src[((co * C_IN + kin) * 3 + kh) * 3 + kw]);
    } else if (idx < 123904) {
        int e = idx - 119808;
        int ks = e & 31, co = (e >> 5) & 63, kb = e >> 11;
        wp[idx] = fbf(ow[co * 64 + kb * 32 + ks]);
    } else if (idx < 132096) {
        int e = idx - 123904;
        int ks = e & 31, co = (e >> 5) & 63, kb = e >> 11;
        wp[idx] = fbf(sw[co * 128 + kb * 32 + ks]);
    } else {
        int e = idx - 132096;
        int ks = e & 31, co = (e >> 5) % 192, kb = e / 6144;
        wp[idx] = fbf(qw[co * 64 + kb * 32 + ks]);
    }
}

// ---------------------------------------------------------------------------
// MFMA 3x3 conv on PRE-NORMALIZED bf16 inputs, FF=4 (proven round 11/12).
// ---------------------------------------------------------------------------
template<int C_IN, int C_OUT, int EPI>
__global__ __launch_bounds__(256) void conv3x3_ff4_k(
    const u16t* __restrict__ s0, const u16t* __restrict__ s1,
    const u16t* __restrict__ s2,
    const u16t* __restrict__ wseg, const float* __restrict__ wb,
    const float* __restrict__ g1, const float* __restrict__ b1,
    const float* __restrict__ m1, const float* __restrict__ v1,
    const float* __restrict__ g2, const float* __restrict__ b2,
    const float* __restrict__ m2, const float* __restrict__ v2,
    int bnoff, u16t* __restrict__ dst1, u16t* __restrict__ dst2)
{
    constexpr int F = 64, T = 512, TT = 64, FF = 4;
    constexpr int NCH  = C_IN / 32;
    constexpr int NCOT = C_OUT / 16;
    constexpr int WT = 9 * NCOT * 64;
    constexpr int XT = 6 * 66 * 4;

    __shared__ __align__(16) u16t s_x[6][66][40];
    __shared__ __align__(16) u16t s_w[WT * 8];

    const int tid = threadIdx.x;
    const int t0 = blockIdx.x * TT;
    const int f0 = blockIdx.y * FF;
    const int b  = blockIdx.z;

    const int l  = tid & 63;
    const int wv = tid >> 6;
    const int lr = l & 15;
    const int lq = l >> 4;

    f32x4 acc[4][NCOT];
#pragma unroll
    for (int i = 0; i < 4; i++)
#pragma unroll
        for (int j = 0; j < NCOT; j++) acc[i][j] = (f32x4){0.f, 0.f, 0.f, 0.f};

    for (int ch = 0; ch < NCH; ch++) {
        if (ch) __syncthreads();

        for (int idx = tid; idx < XT + WT; idx += 256) {
            if (idx < XT) {
                int oct = idx & 3;
                int row = idx >> 2;
                int fr = row / 66;
                int tp = row - fr * 66;
                int fi = f0 + fr - 1;
                int tg = t0 + tp - 1;
                int gc8 = ch * 4 + oct;
                uh8 v = (uh8)0;
                if ((unsigned)fi < (unsigned)F && (unsigned)tg < (unsigned)T) {
                    const u16t* sp; int coff, cw;
                    if (C_IN == 64 || gc8 < 8) { sp = s0; coff = gc8 * 8;        cw = 64; }
                    else if (gc8 < 12)         { sp = s1; coff = (gc8 - 8) * 8;  cw = 32; }
                    else                       { sp = s2; coff = (gc8 - 12) * 8; cw = 32; }
                    v = *(const uh8*)&sp[(((long)b * F + fi) * T + tg) * cw + coff];
                }
                *(uh8*)&s_x[fr][tp][oct * 8] = v;
            } else {
                int w = idx - XT;
                *(uh8*)&s_w[w * 8] = *(const uh8*)&wseg[((long)ch * WT + w) * 8];
            }
        }
        __syncthreads();

#pragma unroll
        for (int kk = 0; kk < 9; kk++) {
            const int kh = kk / 3, kw = kk % 3;
            bfrag A[NCOT];
#pragma unroll
            for (int ct = 0; ct < NCOT; ct++)
                A[ct] = *(const bfrag*)&s_w[((kk * NCOT + ct) * 64 + l) * 8];
#pragma unroll
            for (int ts = 0; ts < 4; ts++) {
                bfrag B = *(const bfrag*)&s_x[wv + kh][ts * 16 + lr + kw][lq * 8];
#pragma unroll
                for (int ct = 0; ct < NCOT; ct++)
                    acc[ts][ct] = __builtin_amdgcn_mfma_f32_16x16x32_bf16(
                        A[ct], B, acc[ts][ct], 0, 0, 0);
            }
        }
    }

    const int f = f0 + wv;
#pragma unroll
    for (int ct = 0; ct < NCOT; ct++) {
        const int co0 = ct * 16 + lq * 4;
        float4 bs = *(const float4*)&wb[co0];
        float sc1[4], sh1[4], sc2[4], sh2[4];
        if (EPI >= 1) {
#pragma unroll
            for (int j = 0; j < 4; j++) {
                int c = bnoff + co0 + j;
                float s = g1[c] * rsqrtf(v1[c] + 1e-5f);
                sc1[j] = s; sh1[j] = b1[c] - m1[c] * s;
            }
        }
        if (EPI == 2) {
#pragma unroll
            for (int j = 0; j < 4; j++) {
                int c = bnoff + co0 + j;
                float s = g2[c] * rsqrtf(v2[c] + 1e-5f);
                sc2[j] = s; sh2[j] = b2[c] - m2[c] * s;
            }
        }
#pragma unroll
        for (int ts = 0; ts < 4; ts++) {
            const int t = t0 + ts * 16 + lr;
            long ob = (((long)b * F + f) * T + t) * C_OUT + co0;
            float a[4];
            a[0] = acc[ts][ct][0] + bs.x;
            a[1] = acc[ts][ct][1] + bs.y;
            a[2] = acc[ts][ct][2] + bs.z;
            a[3] = acc[ts][ct][3] + bs.w;
            if (EPI == 0) {
                uint2 pk;
                pk.x = fbf2(a[0], a[1]);
                pk.y = fbf2(a[2], a[3]);
                *(uint2*)&dst1[ob] = pk;
            } else {
                float n[4];
#pragma unroll
                for (int j = 0; j < 4; j++) {
                    float v = fmaf(a[j], sc1[j], sh1[j]);
                    n[j] = fmaxf(v, 0.01f * v);
                }
                uint2 p1;
                p1.x = fbf2(n[0], n[1]);
                p1.y = fbf2(n[2], n[3]);
                *(uint2*)&dst1[ob] = p1;
                if (EPI == 2) {
#pragma unroll
                    for (int j = 0; j < 4; j++) {
                        float v = fmaf(a[j], sc2[j], sh2[j]);
                        n[j] = fmaxf(v, 0.01f * v);
                    }
                    uint2 p2;
                    p2.x = fbf2(n[0], n[1]);
                    p2.y = fbf2(n[2], n[3]);
                    *(uint2*)&dst2[ob] = p2;
                }
            }
        }
    }
}

// ---------------------------------------------------------------------------
// MFMA qkv projection.  Outputs in MFMA-FRAGMENT layout, per head region of
// 8192 u16 (= T*16):
//  Q,K: idx = kvb*8192 + ((t>>4)*2 + (d>>3))*128 + (t&15)*8 + (d&7)
//  V:   idx = kvb*8192 + ((t>>4)*2 + ((t>>3)&1))*128 + d*8 + (t&7)
// Q pre-scaled by 0.25*log2(e) (exp2-domain softmax).
// ---------------------------------------------------------------------------
__global__ __launch_bounds__(256) void qkv_mfma_k(
    const u16t* __restrict__ ybf, const u16t* __restrict__ wq,
    const float* __restrict__ qbias,
    u16t* __restrict__ q_t, u16t* __restrict__ k_t, u16t* __restrict__ v_t)
{
    constexpr int F = 64, T = 512;
    __shared__ __align__(16) u16t s_y[64][72];
    const int tid = threadIdx.x;
    const int t0 = blockIdx.x * 64;
    const int f = blockIdx.y, b = blockIdx.z;
    const long bf = (long)b * F + f;

    for (int i = tid; i < 512; i += 256) {
        int tt = i >> 3, c0 = (i & 7) * 8;
        *(uh8*)&s_y[tt][c0] = *(const uh8*)&ybf[(bf * T + t0 + tt) * 64 + c0];
    }
    __syncthreads();

    const int l = tid & 63, wv = tid >> 6;
    const int lr = l & 15, lq = l >> 4;
    const int tb = wv * 16 + lr;

    bfrag B0 = *(const bfrag*)&s_y[tb][lq * 8];
    bfrag B1 = *(const bfrag*)&s_y[tb][32 + lq * 8];

    f32x4 acc[12];
#pragma unroll
    for (int i = 0; i < 12; i++) acc[i] = (f32x4){0.f, 0.f, 0.f, 0.f};
#pragma unroll
    for (int ct = 0; ct < 12; ct++) {
        bfrag A0 = *(const bfrag*)&wq[(ct * 16 + lr) * 32 + lq * 8];
        acc[ct] = __builtin_amdgcn_mfma_f32_16x16x32_bf16(A0, B0, acc[ct], 0, 0, 0);
    }
#pragma unroll
    for (int ct = 0; ct < 12; ct++) {
        bfrag A1 = *(const bfrag*)&wq[(192 + ct * 16 + lr) * 32 + lq * 8];
        acc[ct] = __builtin_amdgcn_mfma_f32_16x16x32_bf16(A1, B1, acc[ct], 0, 0, 0);
    }

    const float QS = 0.25f * 1.44269504088896f;
    const int t = t0 + tb;
    const long kvbase = bf * 4;
#pragma unroll
    for (int ct = 0; ct < 12; ct++) {
        int co0 = ct * 16 + lq * 4;
        float4 bi = *(const float4*)&qbias[co0];
        float a0 = acc[ct][0] + bi.x, a1 = acc[ct][1] + bi.y;
        float a2 = acc[ct][2] + bi.z, a3 = acc[ct][3] + bi.w;
        if (co0 < 64) {
            int hh = co0 >> 4, d0 = co0 & 15;
            long idx = (kvbase + hh) * 8192
                     + ((t >> 4) * 2 + (d0 >> 3)) * 128 + (t & 15) * 8 + (d0 & 7);
            uint2 pk;
            pk.x = fbf2(a0 * QS, a1 * QS);
            pk.y = fbf2(a2 * QS, a3 * QS);
            *(uint2*)&q_t[idx] = pk;
        } else if (co0 < 128) {
            int hh = (co0 - 64) >> 4, d0 = (co0 - 64) & 15;
            long idx = (kvbase + hh) * 8192
                     + ((t >> 4) * 2 + (d0 >> 3)) * 128 + (t & 15) * 8 + (d0 & 7);
            uint2 pk;
            pk.x = fbf2(a0, a1);
            pk.y = fbf2(a2, a3);
            *(uint2*)&k_t[idx] = pk;
        } else {
            int hh = (co0 - 128) >> 4, d0 = (co0 - 128) & 15;
            long base = (kvbase + hh) * 8192
                      + ((t >> 4) * 2 + ((t >> 3) & 1)) * 128 + (t & 7);
            v_t[base + (d0 + 0) * 8] = fbf(a0);
            v_t[base + (d0 + 1) * 8] = fbf(a1);
            v_t[base + (d0 + 2) * 8] = fbf(a2);
            v_t[base + (d0 + 3) * 8] = fbf(a3);
        }
    }
}

// ---------------------------------------------------------------------------
// MFMA banded attention: fragment-layout Q/K/V -> every load is a coalesced
// b128 (K/Q: 256B per 16-lane group; V: 256B blocks), no staging.  Masks
// specialized per q-chunk (round 12), exp2 softmax without max-pass
// (round 13).  O written back in the SAME fragment layout at the q-tile
// addresses this block read Q from (in-place alias safe).
// ---------------------------------------------------------------------------
__global__ __launch_bounds__(256) void attn_mfma_k(
    const u16t* __restrict__ qt, const u16t* __restrict__ kt_,
    const u16t* __restrict__ vt, u16t* __restrict__ ob)
{
    constexpr int T = 512, F = 64;
    const int qc = blockIdx.x & 7;
    const int h  = blockIdx.x >> 3;
    const int f = blockIdx.y, b = blockIdx.z;
    const int qb0 = qc * 64;
    const int tid = threadIdx.x;
    const long bf = (long)b * F + f;
    const long kvb = bf * 4 + h;

    __shared__ __align__(16) u16t s_p[4][16][168];

    const int l  = tid & 63;
    const int wv = tid >> 6;
    const int lr = l & 15;
    const int lq = l >> 4;
    const int qt0 = qb0 + wv * 16;

    const u16t* qh = qt  + kvb * 8192;
    const u16t* kh = kt_ + kvb * 8192;
    const u16t* vh = vt  + kvb * 8192;

    // Q fragment (zero rows for lq>=2: d padded 16->32)
    bfrag Bq = (bfrag)0;
    if (lq < 2)
        Bq = *(const bfrag*)&qh[((qt0 >> 4) * 2 + lq) * 128 + lr * 8];

    // K fragments (9 tiles), fully coalesced
    bfrag Kf[9];
    const int kt0 = (qt0 - 64) >> 4;
#pragma unroll
    for (int kti = 0; kti < 9; kti++) {
        if (lq < 2)
            Kf[kti] = *(const bfrag*)&kh[((kt0 + kti) * 2 + lq) * 128 + lr * 8];
        else
            Kf[kti] = (bfrag)0;
    }
    // V fragments (5 tiles of 32 t), fully coalesced
    bfrag Vf[5];
#pragma unroll
    for (int kc = 0; kc < 5; kc++) {
        int t16 = kt0 + kc * 2 + (lq >> 1);
        Vf[kc] = *(const bfrag*)&vh[(t16 * 2 + (lq & 1)) * 128 + lr * 8];
    }

    if (qc == 0) {      // phantom keys p<0: K=0 (score 0, included), V=0
#pragma unroll
        for (int kti = 0; kti < 9; kti++)
            if (qt0 - 64 + kti * 16 < 0) Kf[kti] = (bfrag)0;
#pragma unroll
        for (int kc = 0; kc < 5; kc++)
            if (qt0 - 64 + kc * 32 + lq * 8 < 0) Vf[kc] = (bfrag)0;
    }
    if (qc >= 6) {      // right tail p>=T: V garbage guard (P=0 there)
#pragma unroll
        for (int kc = 0; kc < 5; kc++)
            if (qt0 - 64 + kc * 32 + lq * 8 >= T) Vf[kc] = (bfrag)0;
    }

    f32x4 sf[9];
#pragma unroll
    for (int kti = 0; kti < 9; kti++)
        sf[kti] = __builtin_amdgcn_mfma_f32_16x16x32_bf16(
            Kf[kti], Bq, (f32x4){0.f, 0.f, 0.f, 0.f}, 0, 0, 0);

    if (qc == 7) {
#pragma unroll
        for (int kti = 0; kti < 9; kti++)
#pragma unroll
            for (int j = 0; j < 4; j++) {
                int rk = kti * 16 + lq * 4 + j;
                int dq = rk - lr;
                int p  = qt0 - 64 + rk;
                sf[kti][j] = (dq >= 0 && dq <= 128 && p < T) ? sf[kti][j] : -1.0e30f;
            }
    } else {
#pragma unroll
        for (int j = 0; j < 4; j++) {
            int rk0 = lq * 4 + j;
            if (rk0 < lr)      sf[0][j] = -1.0e30f;   // dq < 0
            if (rk0 > lr)      sf[8][j] = -1.0e30f;   // dq > 128
        }
    }

    // softmax without max-shift (clamp avoids overflow; exp2 domain)
    float lsum = 0.f;
#pragma unroll
    for (int kti = 0; kti < 9; kti++)
#pragma unroll
        for (int j = 0; j < 4; j++) {
            float e = exp2f(fminf(sf[kti][j], 120.f));
            sf[kti][j] = e;
            lsum += e;
        }
    lsum += __shfl_xor(lsum, 16);
    lsum += __shfl_xor(lsum, 32);

#pragma unroll
    for (int kti = 0; kti < 9; kti++) {
        uint2 pp;
        pp.x = fbf2(sf[kti][0], sf[kti][1]);
        pp.y = fbf2(sf[kti][2], sf[kti][3]);
        *(uint2*)&s_p[wv][lr][kti * 16 + lq * 4] = pp;
    }
    {
        uint2 z; z.x = 0; z.y = 0;
        *(uint2*)&s_p[wv][lr][144 + lq * 4] = z;
    }
    __syncthreads();

    f32x4 oa = (f32x4){0.f, 0.f, 0.f, 0.f};
#pragma unroll
    for (int kc = 0; kc < 5; kc++) {
        bfrag Bp = *(const bfrag*)&s_p[wv][lr][kc * 32 + lq * 8];
        oa = __builtin_amdgcn_mfma_f32_16x16x32_bf16(Vf[kc], Bp, oa, 0, 0, 0);
    }
    // O: lane holds O[d = lq*4+j][q = qt0+lr]; write in fragment layout at
    // this block's own q-tile (same region it read Q from -> alias-safe).
    const float inv = rcpf(lsum);
    const int d0 = lq * 4;
    long oidx = kvb * 8192
              + (((qt0 + lr) >> 4) * 2 + (d0 >> 3)) * 128
              + ((qt0 + lr) & 15) * 8 + (d0 & 7);
    uint2 ov;
    ov.x = fbf2(oa[0] * inv, oa[1] * inv);
    ov.y = fbf2(oa[2] * inv, oa[3] * inv);
    *(uint2*)&ob[oidx] = ov;
}

// ---------------------------------------------------------------------------
// MFMA fused o-projection + BN + LeakyReLU + final conv1x1.
// ob input in per-head fragment layout.
// ---------------------------------------------------------------------------
__global__ __launch_bounds__(256) void final_mfma_k(
    const u16t* __restrict__ ob, const u16t* __restrict__ yb,
    const u16t* __restrict__ wo, const float* __restrict__ obias,
    const float* __restrict__ sg, const float* __restrict__ sb,
    const float* __restrict__ sm, const float* __restrict__ sv,
    const u16t* __restrict__ wsao, const float* __restrict__ swb,
    float* __restrict__ out)
{
    constexpr int F = 64, T = 512, TT = 64, P = 72;
    __shared__ __align__(16) u16t s_ob[64][P];
    __shared__ __align__(16) u16t s_y2[64][P];
    __shared__ __align__(16) u16t s_att[64][P];
    __shared__ float s_sc[128], s_sh[128];

    const int tid = threadIdx.x;
    const int t0 = blockIdx.x * TT;
    const int f = blockIdx.y, b = blockIdx.z;
    const long bf = (long)b * F + f;

    if (tid < 128) {
        float sc = sg[tid] * rsqrtf(sv[tid] + 1e-5f);
        s_sc[tid] = sc;
        s_sh[tid] = sb[tid] - sm[tid] * sc;
    }
    __syncthreads();

    for (int i = tid; i < 512; i += 256) {
        int tt = i >> 3, c0 = (i & 7) * 8;
        int t = t0 + tt;
        // ob gather from fragment layout: head = c0>>4, dhalf = (c0>>3)&1
        long oi = (bf * 4 + (c0 >> 4)) * 8192
                + ((t >> 4) * 2 + ((c0 >> 3) & 1)) * 128 + (t & 15) * 8;
        *(uh8*)&s_ob[tt][c0] = *(const uh8*)&ob[oi];
        long gi = (bf * T + t) * 64 + c0;
        uh8 raw = *(const uh8*)&yb[gi];
        float n[8];
#pragma unroll
        for (int j = 0; j < 8; j++) {
            float xv = bfu(raw[j]);
            float xn = fmaf(xv, s_sc[c0 + j], s_sh[c0 + j]);
            n[j] = fmaxf(xn, 0.01f * xn);
        }
        union { uh8 h; unsigned int w[4]; } u;
#pragma unroll
        for (int j4 = 0; j4 < 4; j4++) u.w[j4] = fbf2(n[j4 * 2], n[j4 * 2 + 1]);
        *(uh8*)&s_y2[tt][c0] = u.h;
    }
    __syncthreads();

    const int l  = tid & 63;
    const int wv = tid >> 6;
    const int lr = l & 15;
    const int lq = l >> 4;
    const int tbase = wv * 16 + lr;
    const int cbase = lq * 8;

    f32x4 acc1[4];
#pragma unroll
    for (int i = 0; i < 4; i++) acc1[i] = (f32x4){0.f, 0.f, 0.f, 0.f};
#pragma unroll
    for (int kb = 0; kb < 2; kb++) {
        bfrag B = *(const bfrag*)&s_ob[tbase][kb * 32 + cbase];
#pragma unroll
        for (int ct = 0; ct < 4; ct++) {
            bfrag A = *(const bfrag*)&wo[(kb * 64 + ct * 16 + lr) * 32 + lq * 8];
            acc1[ct] = __builtin_amdgcn_mfma_f32_16x16x32_bf16(A, B, acc1[ct], 0, 0, 0);
        }
    }
#pragma unroll
    for (int ct = 0; ct < 4; ct++) {
        int co = ct * 16 + lq * 4;
        float4 bi = *(const float4*)&obias[co];
        float n[4];
#pragma unroll
        for (int j = 0; j < 4; j++) {
            float a = acc1[ct][j] + ((j == 0) ? bi.x : (j == 1) ? bi.y : (j == 2) ? bi.z : bi.w);
            int cg = 64 + co + j;
            float xn = fmaf(a, s_sc[cg], s_sh[cg]);
            n[j] = fmaxf(xn, 0.01f * xn);
        }
        uint2 pk;
        pk.x = fbf2(n[0], n[1]);
        pk.y = fbf2(n[2], n[3]);
        *(uint2*)&s_att[tbase][co] = pk;
    }
    __syncthreads();

    f32x4 acc2[4];
#pragma unroll
    for (int i = 0; i < 4; i++) acc2[i] = (f32x4){0.f, 0.f, 0.f, 0.f};
#pragma unroll
    for (int kb = 0; kb < 4; kb++) {
        bfrag B = (kb < 2) ? *(const bfrag*)&s_y2[tbase][kb * 32 + cbase]
                           : *(const bfrag*)&s_att[tbase][(kb - 2) * 32 + cbase];
#pragma unroll
        for (int ct = 0; ct < 4; ct++) {
            bfrag A = *(const bfrag*)&wsao[(kb * 64 + ct * 16 + lr) * 32 + lq * 8];
            acc2[ct] = __builtin_amdgcn_mfma_f32_16x16x32_bf16(A, B, acc2[ct], 0, 0, 0);
        }
    }
    const int t = t0 + wv * 16 + lr;
#pragma unroll
    for (int ct = 0; ct < 4; ct++) {
        int co0 = ct * 16 + lq * 4;
        float4 bs = *(const float4*)&swb[co0];
#pragma unroll
        for (int j = 0; j < 4; j++) {
            float bv = (j == 0) ? bs.x : (j == 1) ? bs.y : (j == 2) ? bs.z : bs.w;
            out[(((long)b * 64 + co0 + j) * F + f) * T + t] = acc2[ct][j] + bv;
        }
    }
}

// ---------------------------------------------------------------------------
extern "C" void kernel_launch(void* const* d_in, const int* in_sizes, int n_in,
                              void* d_out, int out_size, void* d_ws, size_t ws_size,
                              hipStream_t stream)
{
    (void)in_sizes; (void)n_in; (void)out_size; (void)ws_size;

    const float* x      = (const float*)d_in[0];
    const float* bd0_g  = (const float*)d_in[1];
    const float* bd0_b  = (const float*)d_in[2];
    const float* bd0_m  = (const float*)d_in[3];
    const float* bd0_v  = (const float*)d_in[4];
    const float* bd0_w  = (const float*)d_in[5];
    const float* bd0_wb = (const float*)d_in[6];
    const float* bd1_g  = (const float*)d_in[7];
    const float* bd1_b  = (const float*)d_in[8];
    const float* bd1_m  = (const float*)d_in[9];
    const float* bd1_v  = (const float*)d_in[10];
    const float* bd1_w  = (const float*)d_in[11];
    const float* bd1_wb = (const float*)d_in[12];
    const float* bdo_g  = (const float*)d_in[13];
    const float* bdo_b  = (const float*)d_in[14];
    const float* bdo_m  = (const float*)d_in[15];
    const float* bdo_v  = (const float*)d_in[16];
    const float* bdo_w  = (const float*)d_in[17];
    const float* bdo_wb = (const float*)d_in[18];
    const float* qkv_w  = (const float*)d_in[19];
    const float* qkv_b  = (const float*)d_in[20];
    const float* o_w    = (const float*)d_in[21];
    const float* o_b    = (const float*)d_in[22];
    const float* sao_g  = (const float*)d_in[23];
    const float* sao_b  = (const float*)d_in[24];
    const float* sao_m  = (const float*)d_in[25];
    const float* sao_v  = (const float*)d_in[26];
    const float* sao_w  = (const float*)d_in[27];
    const float* sao_wb = (const float*)d_in[28];

    char* ws = (char*)d_ws;
    // ws map (bytes), peak 75.8MB (ws >= 83.9MB proven by rounds 2/3):
    //   [0.0 , 16.8M)  xn0  -> ybf (conv2 out; xn0 dead after conv0)
    //   [16.8, 33.6M)  xn1  -> q_t frag (qkv out) -> obf frag (in-place)
    //   [33.6, 50.3M)  xn2  -> k_t frag
    //   [50.3, 58.7M)  a0n1 \ -> v_t frag [50.3,67.1) (dead after conv1/2)
    //   [58.7, 67.1M)  a0n2 /
    //   [67.1, 75.5M)  a1n2
    //   [75.5, 75.8M)  wpack bf16 (144384 entries)
    u16t* xn0  = (u16t*)(ws);
    u16t* xn1  = (u16t*)(ws + 16777216);
    u16t* xn2  = (u16t*)(ws + 33554432);
    u16t* a0n1 = (u16t*)(ws + 50331648);
    u16t* a0n2 = (u16t*)(ws + 58720256);
    u16t* a1n2 = (u16t*)(ws + 67108864);
    u16t* ybf  = xn0;
    u16t* q_t  = xn1;
    u16t* k_t  = xn2;
    u16t* v_t  = a0n1;
    u16t* obf  = q_t;                      // in-place alias (fragment layout)
    u16t* wpk  = (u16t*)(ws + 75497472);

    dim3 blk(256);
    dim3 gprep(8, 64, 4);   // T/64, F, B
    dim3 gconv(8, 16, 4);   // T/64, F/4, B

    hipLaunchKernelGGL(prep_x3_k, gprep, blk, 0, stream, x,
        bd0_g, bd0_b, bd0_m, bd0_v, bd1_g, bd1_b, bd1_m, bd1_v,
        bdo_g, bdo_b, bdo_m, bdo_v, xn0, xn1, xn2);
    hipLaunchKernelGGL(prep_w_k, dim3(564), blk, 0, stream,
        bd0_w, bd1_w, bdo_w, o_w, sao_w, qkv_w, wpk);
    hipLaunchKernelGGL((conv3x3_ff4_k<64, 32, 2>), gconv, blk, 0, stream,
        xn0, nullptr, nullptr, wpk, bd0_wb,
        bd1_g, bd1_b, bd1_m, bd1_v, bdo_g, bdo_b, bdo_m, bdo_v,
        64, a0n1, a0n2);
    hipLaunchKernelGGL((conv3x3_ff4_k<96, 32, 1>), gconv, blk, 0, stream,
        xn1, a0n1, nullptr, wpk + 18432, bd1_wb,
        bdo_g, bdo_b, bdo_m, bdo_v, nullptr, nullptr, nullptr, nullptr,
        96, a1n2, nullptr);
    hipLaunchKernelGGL((conv3x3_ff4_k<128, 64, 0>), gconv, blk, 0, stream,
        xn2, a0n2, a1n2, wpk + 46080, bdo_wb,
        nullptr, nullptr, nullptr, nullptr, nullptr, nullptr, nullptr, nullptr,
        0, ybf, nullptr);
    hipLaunchKernelGGL(qkv_mfma_k, gprep, blk, 0, stream,
        ybf, wpk + 132096, qkv_b, q_t, k_t, v_t);
    hipLaunchKernelGGL(attn_mfma_k, dim3(32, 64, 4), blk, 0, stream,
        q_t, k_t, v_t, obf);
    hipLaunchKernelGGL(final_mfma_k, gprep, blk, 0, stream,
        obf, ybf, wpk + 119808, o_b, sao_g, sao_b, sao_m, sao_v,
        wpk + 123904, sao_wb, (float*)d_out);
}

// Round 19
// 172.249 us; speedup vs baseline: 1.0335x; 1.0335x over previous
//
#include <hip/hip_runtime.h>
#include <hip/hip_bf16.h>

typedef unsigned short u16t;
typedef __attribute__((ext_vector_type(8))) short bfrag;      // 8 bf16 bits
typedef __attribute__((ext_vector_type(4))) float f32x4;      // MFMA acc
typedef __attribute__((ext_vector_type(8))) unsigned short uh8;

__device__ __forceinline__ float bfu(u16t u) {
    union { unsigned int i; float f; } c;
    c.i = ((unsigned int)u) << 16;
    return c.f;
}
__device__ __forceinline__ u16t fbf(float f) {
    __hip_bfloat16 h = __float2bfloat16(f);
    return *reinterpret_cast<u16t*>(&h);
}
// HW packed f32x2 -> bf16x2 (single VALU op)
__device__ __forceinline__ unsigned int fbf2(float lo, float hi) {
    unsigned int r;
    asm("v_cvt_pk_bf16_f32 %0, %1, %2" : "=v"(r) : "v"(lo), "v"(hi));
    return r;
}
__device__ __forceinline__ float rcpf(float x) {
    float r;
    asm("v_rcp_f32 %0, %1" : "=v"(r) : "v"(x));
    return r;
}
// HW 2^x (single transcendental VALU op; ~1 ulp — exactly our exp2 domain)
__device__ __forceinline__ float exp2hw(float x) {
    float r;
    asm("v_exp_f32 %0, %1" : "=v"(r) : "v"(x));
    return r;
}

// ---------------------------------------------------------------------------
// x [b][64c][64f][512t] fp32 -> three normalized bf16 copies in [b][f][t][64]
// ---------------------------------------------------------------------------
__global__ __launch_bounds__(256) void prep_x3_k(
    const float* __restrict__ x,
    const float* __restrict__ g0, const float* __restrict__ b0,
    const float* __restrict__ m0, const float* __restrict__ v0,
    const float* __restrict__ g1, const float* __restrict__ b1,
    const float* __restrict__ m1, const float* __restrict__ v1,
    const float* __restrict__ g2, const float* __restrict__ b2,
    const float* __restrict__ m2, const float* __restrict__ v2,
    u16t* __restrict__ xn0, u16t* __restrict__ xn1, u16t* __restrict__ xn2)
{
    constexpr int F = 64, T = 512;
    __shared__ u16t su[64][74];
    __shared__ float ssc[3][64], ssh[3][64];
    const int tid = threadIdx.x;
    const int t0 = blockIdx.x * 64;
    const int f = blockIdx.y, b = blockIdx.z;

    if (tid < 64) {
        int c = tid;
        float s;
        s = g0[c] * rsqrtf(v0[c] + 1e-5f); ssc[0][c] = s; ssh[0][c] = b0[c] - m0[c] * s;
        s = g1[c] * rsqrtf(v1[c] + 1e-5f); ssc[1][c] = s; ssh[1][c] = b1[c] - m1[c] * s;
        s = g2[c] * rsqrtf(v2[c] + 1e-5f); ssc[2][c] = s; ssh[2][c] = b2[c] - m2[c] * s;
    }
#pragma unroll
    for (int p = 0; p < 16; p++) {
        int i = tid + 256 * p;
        int c = i >> 6, t = i & 63;
        su[c][t] = fbf(x[(((long)b * 64 + c) * F + f) * T + t0 + t]);
    }
    __syncthreads();
#pragma unroll
    for (int p = 0; p < 2; p++) {
        int i = tid + 256 * p;
        int t = i >> 3, c8 = i & 7;
        float n0[8], n1[8], n2[8];
#pragma unroll
        for (int j = 0; j < 8; j++) {
            int c = c8 * 8 + j;
            float xv = bfu(su[c][t]);
            float a0 = fmaf(xv, ssc[0][c], ssh[0][c]);
            float a1 = fmaf(xv, ssc[1][c], ssh[1][c]);
            float a2 = fmaf(xv, ssc[2][c], ssh[2][c]);
            n0[j] = fmaxf(a0, 0.01f * a0);
            n1[j] = fmaxf(a1, 0.01f * a1);
            n2[j] = fmaxf(a2, 0.01f * a2);
        }
        union { uh8 h; unsigned int w[4]; } u0, u1, u2;
#pragma unroll
        for (int j4 = 0; j4 < 4; j4++) {
            u0.w[j4] = fbf2(n0[j4 * 2], n0[j4 * 2 + 1]);
            u1.w[j4] = fbf2(n1[j4 * 2], n1[j4 * 2 + 1]);
            u2.w[j4] = fbf2(n2[j4 * 2], n2[j4 * 2 + 1]);
        }
        long gi = (((long)b * F + f) * T + t0 + t) * 64 + c8 * 8;
        *(uh8*)&xn0[gi] = u0.h;
        *(uh8*)&xn1[gi] = u1.h;
        *(uh8*)&xn2[gi] = u2.h;
    }
}

// ---------------------------------------------------------------------------
// Pack weights fp32 -> bf16 fragments (layout proven round 10).
// ---------------------------------------------------------------------------
__global__ __launch_bounds__(256) void prep_w_k(
    const float* __restrict__ w0, const float* __restrict__ w1,
    const float* __restrict__ w2, const float* __restrict__ ow,
    const float* __restrict__ sw, const float* __restrict__ qw,
    u16t* __restrict__ wp)
{
    int idx = blockIdx.x * 256 + threadIdx.x;
    if (idx >= 144384) return;
    if (idx < 119808) {
        int C_IN, C_OUT, e;
        const float* src;
        if (idx < 18432)      { C_IN = 64;  C_OUT = 32; src = w0; e = idx; }
        else if (idx < 46080) { C_IN = 96;  C_OUT = 32; src = w1; e = idx - 18432; }
        else                  { C_IN = 128; C_OUT = 64; src = w2; e = idx - 46080; }
        int NCOT = C_OUT / 16;
        int j  = e & 7;
        int l  = (e >> 3) & 63;
        int r  = e >> 9;
        int ct = r % NCOT;
        int r2 = r / NCOT;
        int kk = r2 % 9;
        int cb = r2 / 9;
        int co  = ct * 16 + (l & 15);
        int kin = cb * 32 + (l >> 4) * 8 + j;
        int kh = kk / 3, kw = kk % 3;
        wp[idx] = fbf(src[((co * C_IN + kin) * 3 + kh) * 3 + kw]);
    } else if (idx < 123904) {
        int e = idx - 119808;
        int ks = e & 31, co = (e >> 5) & 63, kb = e >> 11;
        wp[idx] = fbf(ow[co * 64 + kb * 32 + ks]);
    } else if (idx < 132096) {
        int e = idx - 123904;
        int ks = e & 31, co = (e >> 5) & 63, kb = e >> 11;
        wp[idx] = fbf(sw[co * 128 + kb * 32 + ks]);
    } else {
        int e = idx - 132096;
        int ks = e & 31, co = (e >> 5) % 192, kb = e / 6144;
        wp[idx] = fbf(qw[co * 64 + kb * 32 + ks]);
    }
}

// ---------------------------------------------------------------------------
// MFMA 3x3 conv on PRE-NORMALIZED bf16 inputs, FF=4 (proven round 11/12).
// ---------------------------------------------------------------------------
template<int C_IN, int C_OUT, int EPI>
__global__ __launch_bounds__(256) void conv3x3_ff4_k(
    const u16t* __restrict__ s0, const u16t* __restrict__ s1,
    const u16t* __restrict__ s2,
    const u16t* __restrict__ wseg, const float* __restrict__ wb,
    const float* __restrict__ g1, const float* __restrict__ b1,
    const float* __restrict__ m1, const float* __restrict__ v1,
    const float* __restrict__ g2, const float* __restrict__ b2,
    const float* __restrict__ m2, const float* __restrict__ v2,
    int bnoff, u16t* __restrict__ dst1, u16t* __restrict__ dst2)
{
    constexpr int F = 64, T = 512, TT = 64, FF = 4;
    constexpr int NCH  = C_IN / 32;
    constexpr int NCOT = C_OUT / 16;
    constexpr int WT = 9 * NCOT * 64;
    constexpr int XT = 6 * 66 * 4;

    __shared__ __align__(16) u16t s_x[6][66][40];
    __shared__ __align__(16) u16t s_w[WT * 8];

    const int tid = threadIdx.x;
    const int t0 = blockIdx.x * TT;
    const int f0 = blockIdx.y * FF;
    const int b  = blockIdx.z;

    const int l  = tid & 63;
    const int wv = tid >> 6;
    const int lr = l & 15;
    const int lq = l >> 4;

    f32x4 acc[4][NCOT];
#pragma unroll
    for (int i = 0; i < 4; i++)
#pragma unroll
        for (int j = 0; j < NCOT; j++) acc[i][j] = (f32x4){0.f, 0.f, 0.f, 0.f};

    for (int ch = 0; ch < NCH; ch++) {
        if (ch) __syncthreads();

        for (int idx = tid; idx < XT + WT; idx += 256) {
            if (idx < XT) {
                int oct = idx & 3;
                int row = idx >> 2;
                int fr = row / 66;
                int tp = row - fr * 66;
                int fi = f0 + fr - 1;
                int tg = t0 + tp - 1;
                int gc8 = ch * 4 + oct;
                uh8 v = (uh8)0;
                if ((unsigned)fi < (unsigned)F && (unsigned)tg < (unsigned)T) {
                    const u16t* sp; int coff, cw;
                    if (C_IN == 64 || gc8 < 8) { sp = s0; coff = gc8 * 8;        cw = 64; }
                    else if (gc8 < 12)         { sp = s1; coff = (gc8 - 8) * 8;  cw = 32; }
                    else                       { sp = s2; coff = (gc8 - 12) * 8; cw = 32; }
                    v = *(const uh8*)&sp[(((long)b * F + fi) * T + tg) * cw + coff];
                }
                *(uh8*)&s_x[fr][tp][oct * 8] = v;
            } else {
                int w = idx - XT;
                *(uh8*)&s_w[w * 8] = *(const uh8*)&wseg[((long)ch * WT + w) * 8];
            }
        }
        __syncthreads();

#pragma unroll
        for (int kk = 0; kk < 9; kk++) {
            const int kh = kk / 3, kw = kk % 3;
            bfrag A[NCOT];
#pragma unroll
            for (int ct = 0; ct < NCOT; ct++)
                A[ct] = *(const bfrag*)&s_w[((kk * NCOT + ct) * 64 + l) * 8];
#pragma unroll
            for (int ts = 0; ts < 4; ts++) {
                bfrag B = *(const bfrag*)&s_x[wv + kh][ts * 16 + lr + kw][lq * 8];
#pragma unroll
                for (int ct = 0; ct < NCOT; ct++)
                    acc[ts][ct] = __builtin_amdgcn_mfma_f32_16x16x32_bf16(
                        A[ct], B, acc[ts][ct], 0, 0, 0);
            }
        }
    }

    const int f = f0 + wv;
#pragma unroll
    for (int ct = 0; ct < NCOT; ct++) {
        const int co0 = ct * 16 + lq * 4;
        float4 bs = *(const float4*)&wb[co0];
        float sc1[4], sh1[4], sc2[4], sh2[4];
        if (EPI >= 1) {
#pragma unroll
            for (int j = 0; j < 4; j++) {
                int c = bnoff + co0 + j;
                float s = g1[c] * rsqrtf(v1[c] + 1e-5f);
                sc1[j] = s; sh1[j] = b1[c] - m1[c] * s;
            }
        }
        if (EPI == 2) {
#pragma unroll
            for (int j = 0; j < 4; j++) {
                int c = bnoff + co0 + j;
                float s = g2[c] * rsqrtf(v2[c] + 1e-5f);
                sc2[j] = s; sh2[j] = b2[c] - m2[c] * s;
            }
        }
#pragma unroll
        for (int ts = 0; ts < 4; ts++) {
            const int t = t0 + ts * 16 + lr;
            long ob = (((long)b * F + f) * T + t) * C_OUT + co0;
            float a[4];
            a[0] = acc[ts][ct][0] + bs.x;
            a[1] = acc[ts][ct][1] + bs.y;
            a[2] = acc[ts][ct][2] + bs.z;
            a[3] = acc[ts][ct][3] + bs.w;
            if (EPI == 0) {
                uint2 pk;
                pk.x = fbf2(a[0], a[1]);
                pk.y = fbf2(a[2], a[3]);
                *(uint2*)&dst1[ob] = pk;
            } else {
                float n[4];
#pragma unroll
                for (int j = 0; j < 4; j++) {
                    float v = fmaf(a[j], sc1[j], sh1[j]);
                    n[j] = fmaxf(v, 0.01f * v);
                }
                uint2 p1;
                p1.x = fbf2(n[0], n[1]);
                p1.y = fbf2(n[2], n[3]);
                *(uint2*)&dst1[ob] = p1;
                if (EPI == 2) {
#pragma unroll
                    for (int j = 0; j < 4; j++) {
                        float v = fmaf(a[j], sc2[j], sh2[j]);
                        n[j] = fmaxf(v, 0.01f * v);
                    }
                    uint2 p2;
                    p2.x = fbf2(n[0], n[1]);
                    p2.y = fbf2(n[2], n[3]);
                    *(uint2*)&dst2[ob] = p2;
                }
            }
        }
    }
}

// ---------------------------------------------------------------------------
// MFMA qkv projection.  Outputs in MFMA-FRAGMENT layout, per head region of
// 8192 u16 (= T*16):
//  Q,K: idx = kvb*8192 + ((t>>4)*2 + (d>>3))*128 + (t&15)*8 + (d&7)
//  V:   idx = kvb*8192 + ((t>>4)*2 + ((t>>3)&1))*128 + d*8 + (t&7)
// Q pre-scaled by 0.25*log2(e) (exp2-domain softmax).
// ---------------------------------------------------------------------------
__global__ __launch_bounds__(256) void qkv_mfma_k(
    const u16t* __restrict__ ybf, const u16t* __restrict__ wq,
    const float* __restrict__ qbias,
    u16t* __restrict__ q_t, u16t* __restrict__ k_t, u16t* __restrict__ v_t)
{
    constexpr int F = 64, T = 512;
    __shared__ __align__(16) u16t s_y[64][72];
    const int tid = threadIdx.x;
    const int t0 = blockIdx.x * 64;
    const int f = blockIdx.y, b = blockIdx.z;
    const long bf = (long)b * F + f;

    for (int i = tid; i < 512; i += 256) {
        int tt = i >> 3, c0 = (i & 7) * 8;
        *(uh8*)&s_y[tt][c0] = *(const uh8*)&ybf[(bf * T + t0 + tt) * 64 + c0];
    }
    __syncthreads();

    const int l = tid & 63, wv = tid >> 6;
    const int lr = l & 15, lq = l >> 4;
    const int tb = wv * 16 + lr;

    bfrag B0 = *(const bfrag*)&s_y[tb][lq * 8];
    bfrag B1 = *(const bfrag*)&s_y[tb][32 + lq * 8];

    f32x4 acc[12];
#pragma unroll
    for (int i = 0; i < 12; i++) acc[i] = (f32x4){0.f, 0.f, 0.f, 0.f};
#pragma unroll
    for (int ct = 0; ct < 12; ct++) {
        bfrag A0 = *(const bfrag*)&wq[(ct * 16 + lr) * 32 + lq * 8];
        acc[ct] = __builtin_amdgcn_mfma_f32_16x16x32_bf16(A0, B0, acc[ct], 0, 0, 0);
    }
#pragma unroll
    for (int ct = 0; ct < 12; ct++) {
        bfrag A1 = *(const bfrag*)&wq[(192 + ct * 16 + lr) * 32 + lq * 8];
        acc[ct] = __builtin_amdgcn_mfma_f32_16x16x32_bf16(A1, B1, acc[ct], 0, 0, 0);
    }

    const float QS = 0.25f * 1.44269504088896f;
    const int t = t0 + tb;
    const long kvbase = bf * 4;
#pragma unroll
    for (int ct = 0; ct < 12; ct++) {
        int co0 = ct * 16 + lq * 4;
        float4 bi = *(const float4*)&qbias[co0];
        float a0 = acc[ct][0] + bi.x, a1 = acc[ct][1] + bi.y;
        float a2 = acc[ct][2] + bi.z, a3 = acc[ct][3] + bi.w;
        if (co0 < 64) {
            int hh = co0 >> 4, d0 = co0 & 15;
            long idx = (kvbase + hh) * 8192
                     + ((t >> 4) * 2 + (d0 >> 3)) * 128 + (t & 15) * 8 + (d0 & 7);
            uint2 pk;
            pk.x = fbf2(a0 * QS, a1 * QS);
            pk.y = fbf2(a2 * QS, a3 * QS);
            *(uint2*)&q_t[idx] = pk;
        } else if (co0 < 128) {
            int hh = (co0 - 64) >> 4, d0 = (co0 - 64) & 15;
            long idx = (kvbase + hh) * 8192
                     + ((t >> 4) * 2 + (d0 >> 3)) * 128 + (t & 15) * 8 + (d0 & 7);
            uint2 pk;
            pk.x = fbf2(a0, a1);
            pk.y = fbf2(a2, a3);
            *(uint2*)&k_t[idx] = pk;
        } else {
            int hh = (co0 - 128) >> 4, d0 = (co0 - 128) & 15;
            long base = (kvbase + hh) * 8192
                      + ((t >> 4) * 2 + ((t >> 3) & 1)) * 128 + (t & 7);
            v_t[base + (d0 + 0) * 8] = fbf(a0);
            v_t[base + (d0 + 1) * 8] = fbf(a1);
            v_t[base + (d0 + 2) * 8] = fbf(a2);
            v_t[base + (d0 + 3) * 8] = fbf(a3);
        }
    }
}

// ---------------------------------------------------------------------------
// MFMA banded attention: fragment-layout Q/K/V -> every load is a coalesced
// b128 (K/Q: 256B per 16-lane group; V: 256B blocks), no staging.  Masks
// specialized per q-chunk (round 12), exp2 softmax without max-pass via
// hardware v_exp_f32.  O written back in the SAME fragment layout at the
// q-tile addresses this block read Q from (in-place alias safe).
// ---------------------------------------------------------------------------
__global__ __launch_bounds__(256) void attn_mfma_k(
    const u16t* __restrict__ qt, const u16t* __restrict__ kt_,
    const u16t* __restrict__ vt, u16t* __restrict__ ob)
{
    constexpr int T = 512, F = 64;
    const int qc = blockIdx.x & 7;
    const int h  = blockIdx.x >> 3;
    const int f = blockIdx.y, b = blockIdx.z;
    const int qb0 = qc * 64;
    const int tid = threadIdx.x;
    const long bf = (long)b * F + f;
    const long kvb = bf * 4 + h;

    __shared__ __align__(16) u16t s_p[4][16][168];

    const int l  = tid & 63;
    const int wv = tid >> 6;
    const int lr = l & 15;
    const int lq = l >> 4;
    const int qt0 = qb0 + wv * 16;

    const u16t* qh = qt  + kvb * 8192;
    const u16t* kh = kt_ + kvb * 8192;
    const u16t* vh = vt  + kvb * 8192;

    // Q fragment (zero rows for lq>=2: d padded 16->32)
    bfrag Bq = (bfrag)0;
    if (lq < 2)
        Bq = *(const bfrag*)&qh[((qt0 >> 4) * 2 + lq) * 128 + lr * 8];

    // K fragments (9 tiles), fully coalesced
    bfrag Kf[9];
    const int kt0 = (qt0 - 64) >> 4;
#pragma unroll
    for (int kti = 0; kti < 9; kti++) {
        if (lq < 2)
            Kf[kti] = *(const bfrag*)&kh[((kt0 + kti) * 2 + lq) * 128 + lr * 8];
        else
            Kf[kti] = (bfrag)0;
    }
    // V fragments (5 tiles of 32 t), fully coalesced
    bfrag Vf[5];
#pragma unroll
    for (int kc = 0; kc < 5; kc++) {
        int t16 = kt0 + kc * 2 + (lq >> 1);
        Vf[kc] = *(const bfrag*)&vh[(t16 * 2 + (lq & 1)) * 128 + lr * 8];
    }

    if (qc == 0) {      // phantom keys p<0: K=0 (score 0, included), V=0
#pragma unroll
        for (int kti = 0; kti < 9; kti++)
            if (qt0 - 64 + kti * 16 < 0) Kf[kti] = (bfrag)0;
#pragma unroll
        for (int kc = 0; kc < 5; kc++)
            if (qt0 - 64 + kc * 32 + lq * 8 < 0) Vf[kc] = (bfrag)0;
    }
    if (qc >= 6) {      // right tail p>=T: V garbage guard (P=0 there)
#pragma unroll
        for (int kc = 0; kc < 5; kc++)
            if (qt0 - 64 + kc * 32 + lq * 8 >= T) Vf[kc] = (bfrag)0;
    }

    f32x4 sf[9];
#pragma unroll
    for (int kti = 0; kti < 9; kti++)
        sf[kti] = __builtin_amdgcn_mfma_f32_16x16x32_bf16(
            Kf[kti], Bq, (f32x4){0.f, 0.f, 0.f, 0.f}, 0, 0, 0);

    if (qc == 7) {
#pragma unroll
        for (int kti = 0; kti < 9; kti++)
#pragma unroll
            for (int j = 0; j < 4; j++) {
                int rk = kti * 16 + lq * 4 + j;
                int dq = rk - lr;
                int p  = qt0 - 64 + rk;
                sf[kti][j] = (dq >= 0 && dq <= 128 && p < T) ? sf[kti][j] : -1.0e30f;
            }
    } else {
#pragma unroll
        for (int j = 0; j < 4; j++) {
            int rk0 = lq * 4 + j;
            if (rk0 < lr)      sf[0][j] = -1.0e30f;   // dq < 0
            if (rk0 > lr)      sf[8][j] = -1.0e30f;   // dq > 128
        }
    }

    // softmax without max-shift (clamp avoids overflow; exp2 domain via
    // hardware v_exp_f32 - single instruction per score)
    float lsum = 0.f;
#pragma unroll
    for (int kti = 0; kti < 9; kti++)
#pragma unroll
        for (int j = 0; j < 4; j++) {
            float e = exp2hw(fminf(sf[kti][j], 120.f));
            sf[kti][j] = e;
            lsum += e;
        }
    lsum += __shfl_xor(lsum, 16);
    lsum += __shfl_xor(lsum, 32);

#pragma unroll
    for (int kti = 0; kti < 9; kti++) {
        uint2 pp;
        pp.x = fbf2(sf[kti][0], sf[kti][1]);
        pp.y = fbf2(sf[kti][2], sf[kti][3]);
        *(uint2*)&s_p[wv][lr][kti * 16 + lq * 4] = pp;
    }
    {
        uint2 z; z.x = 0; z.y = 0;
        *(uint2*)&s_p[wv][lr][144 + lq * 4] = z;
    }
    __syncthreads();

    f32x4 oa = (f32x4){0.f, 0.f, 0.f, 0.f};
#pragma unroll
    for (int kc = 0; kc < 5; kc++) {
        bfrag Bp = *(const bfrag*)&s_p[wv][lr][kc * 32 + lq * 8];
        oa = __builtin_amdgcn_mfma_f32_16x16x32_bf16(Vf[kc], Bp, oa, 0, 0, 0);
    }
    // O: lane holds O[d = lq*4+j][q = qt0+lr]; write in fragment layout at
    // this block's own q-tile (same region it read Q from -> alias-safe).
    const float inv = rcpf(lsum);
    const int d0 = lq * 4;
    long oidx = kvb * 8192
              + (((qt0 + lr) >> 4) * 2 + (d0 >> 3)) * 128
              + ((qt0 + lr) & 15) * 8 + (d0 & 7);
    uint2 ov;
    ov.x = fbf2(oa[0] * inv, oa[1] * inv);
    ov.y = fbf2(oa[2] * inv, oa[3] * inv);
    *(uint2*)&ob[oidx] = ov;
}

// ---------------------------------------------------------------------------
// MFMA fused o-projection + BN + LeakyReLU + final conv1x1.
// ob input in per-head fragment layout.
// ---------------------------------------------------------------------------
__global__ __launch_bounds__(256) void final_mfma_k(
    const u16t* __restrict__ ob, const u16t* __restrict__ yb,
    const u16t* __restrict__ wo, const float* __restrict__ obias,
    const float* __restrict__ sg, const float* __restrict__ sb,
    const float* __restrict__ sm, const float* __restrict__ sv,
    const u16t* __restrict__ wsao, const float* __restrict__ swb,
    float* __restrict__ out)
{
    constexpr int F = 64, T = 512, TT = 64, P = 72;
    __shared__ __align__(16) u16t s_ob[64][P];
    __shared__ __align__(16) u16t s_y2[64][P];
    __shared__ __align__(16) u16t s_att[64][P];
    __shared__ float s_sc[128], s_sh[128];

    const int tid = threadIdx.x;
    const int t0 = blockIdx.x * TT;
    const int f = blockIdx.y, b = blockIdx.z;
    const long bf = (long)b * F + f;

    if (tid < 128) {
        float sc = sg[tid] * rsqrtf(sv[tid] + 1e-5f);
        s_sc[tid] = sc;
        s_sh[tid] = sb[tid] - sm[tid] * sc;
    }
    __syncthreads();

    for (int i = tid; i < 512; i += 256) {
        int tt = i >> 3, c0 = (i & 7) * 8;
        int t = t0 + tt;
        // ob gather from fragment layout: head = c0>>4, dhalf = (c0>>3)&1
        long oi = (bf * 4 + (c0 >> 4)) * 8192
                + ((t >> 4) * 2 + ((c0 >> 3) & 1)) * 128 + (t & 15) * 8;
        *(uh8*)&s_ob[tt][c0] = *(const uh8*)&ob[oi];
        long gi = (bf * T + t) * 64 + c0;
        uh8 raw = *(const uh8*)&yb[gi];
        float n[8];
#pragma unroll
        for (int j = 0; j < 8; j++) {
            float xv = bfu(raw[j]);
            float xn = fmaf(xv, s_sc[c0 + j], s_sh[c0 + j]);
            n[j] = fmaxf(xn, 0.01f * xn);
        }
        union { uh8 h; unsigned int w[4]; } u;
#pragma unroll
        for (int j4 = 0; j4 < 4; j4++) u.w[j4] = fbf2(n[j4 * 2], n[j4 * 2 + 1]);
        *(uh8*)&s_y2[tt][c0] = u.h;
    }
    __syncthreads();

    const int l  = tid & 63;
    const int wv = tid >> 6;
    const int lr = l & 15;
    const int lq = l >> 4;
    const int tbase = wv * 16 + lr;
    const int cbase = lq * 8;

    f32x4 acc1[4];
#pragma unroll
    for (int i = 0; i < 4; i++) acc1[i] = (f32x4){0.f, 0.f, 0.f, 0.f};
#pragma unroll
    for (int kb = 0; kb < 2; kb++) {
        bfrag B = *(const bfrag*)&s_ob[tbase][kb * 32 + cbase];
#pragma unroll
        for (int ct = 0; ct < 4; ct++) {
            bfrag A = *(const bfrag*)&wo[(kb * 64 + ct * 16 + lr) * 32 + lq * 8];
            acc1[ct] = __builtin_amdgcn_mfma_f32_16x16x32_bf16(A, B, acc1[ct], 0, 0, 0);
        }
    }
#pragma unroll
    for (int ct = 0; ct < 4; ct++) {
        int co = ct * 16 + lq * 4;
        float4 bi = *(const float4*)&obias[co];
        float n[4];
#pragma unroll
        for (int j = 0; j < 4; j++) {
            float a = acc1[ct][j] + ((j == 0) ? bi.x : (j == 1) ? bi.y : (j == 2) ? bi.z : bi.w);
            int cg = 64 + co + j;
            float xn = fmaf(a, s_sc[cg], s_sh[cg]);
            n[j] = fmaxf(xn, 0.01f * xn);
        }
        uint2 pk;
        pk.x = fbf2(n[0], n[1]);
        pk.y = fbf2(n[2], n[3]);
        *(uint2*)&s_att[tbase][co] = pk;
    }
    __syncthreads();

    f32x4 acc2[4];
#pragma unroll
    for (int i = 0; i < 4; i++) acc2[i] = (f32x4){0.f, 0.f, 0.f, 0.f};
#pragma unroll
    for (int kb = 0; kb < 4; kb++) {
        bfrag B = (kb < 2) ? *(const bfrag*)&s_y2[tbase][kb * 32 + cbase]
                           : *(const bfrag*)&s_att[tbase][(kb - 2) * 32 + cbase];
#pragma unroll
        for (int ct = 0; ct < 4; ct++) {
            bfrag A = *(const bfrag*)&wsao[(kb * 64 + ct * 16 + lr) * 32 + lq * 8];
            acc2[ct] = __builtin_amdgcn_mfma_f32_16x16x32_bf16(A, B, acc2[ct], 0, 0, 0);
        }
    }
    const int t = t0 + wv * 16 + lr;
#pragma unroll
    for (int ct = 0; ct < 4; ct++) {
        int co0 = ct * 16 + lq * 4;
        float4 bs = *(const float4*)&swb[co0];
#pragma unroll
        for (int j = 0; j < 4; j++) {
            float bv = (j == 0) ? bs.x : (j == 1) ? bs.y : (j == 2) ? bs.z : bs.w;
            out[(((long)b * 64 + co0 + j) * F + f) * T + t] = acc2[ct][j] + bv;
        }
    }
}

// ---------------------------------------------------------------------------
extern "C" void kernel_launch(void* const* d_in, const int* in_sizes, int n_in,
                              void* d_out, int out_size, void* d_ws, size_t ws_size,
                              hipStream_t stream)
{
    (void)in_sizes; (void)n_in; (void)out_size; (void)ws_size;

    const float* x      = (const float*)d_in[0];
    const float* bd0_g  = (const float*)d_in[1];
    const float* bd0_b  = (const float*)d_in[2];
    const float* bd0_m  = (const float*)d_in[3];
    const float* bd0_v  = (const float*)d_in[4];
    const float* bd0_w  = (const float*)d_in[5];
    const float* bd0_wb = (const float*)d_in[6];
    const float* bd1_g  = (const float*)d_in[7];
    const float* bd1_b  = (const float*)d_in[8];
    const float* bd1_m  = (const float*)d_in[9];
    const float* bd1_v  = (const float*)d_in[10];
    const float* bd1_w  = (const float*)d_in[11];
    const float* bd1_wb = (const float*)d_in[12];
    const float* bdo_g  = (const float*)d_in[13];
    const float* bdo_b  = (const float*)d_in[14];
    const float* bdo_m  = (const float*)d_in[15];
    const float* bdo_v  = (const float*)d_in[16];
    const float* bdo_w  = (const float*)d_in[17];
    const float* bdo_wb = (const float*)d_in[18];
    const float* qkv_w  = (const float*)d_in[19];
    const float* qkv_b  = (const float*)d_in[20];
    const float* o_w    = (const float*)d_in[21];
    const float* o_b    = (const float*)d_in[22];
    const float* sao_g  = (const float*)d_in[23];
    const float* sao_b  = (const float*)d_in[24];
    const float* sao_m  = (const float*)d_in[25];
    const float* sao_v  = (const float*)d_in[26];
    const float* sao_w  = (const float*)d_in[27];
    const float* sao_wb = (const float*)d_in[28];

    char* ws = (char*)d_ws;
    // ws map (bytes), peak 75.8MB (ws >= 83.9MB proven by rounds 2/3):
    //   [0.0 , 16.8M)  xn0  -> ybf (conv2 out; xn0 dead after conv0)
    //   [16.8, 33.6M)  xn1  -> q_t frag (qkv out) -> obf frag (in-place)
    //   [33.6, 50.3M)  xn2  -> k_t frag
    //   [50.3, 58.7M)  a0n1 \ -> v_t frag [50.3,67.1) (dead after conv1/2)
    //   [58.7, 67.1M)  a0n2 /
    //   [67.1, 75.5M)  a1n2
    //   [75.5, 75.8M)  wpack bf16 (144384 entries)
    u16t* xn0  = (u16t*)(ws);
    u16t* xn1  = (u16t*)(ws + 16777216);
    u16t* xn2  = (u16t*)(ws + 33554432);
    u16t* a0n1 = (u16t*)(ws + 50331648);
    u16t* a0n2 = (u16t*)(ws + 58720256);
    u16t* a1n2 = (u16t*)(ws + 67108864);
    u16t* ybf  = xn0;
    u16t* q_t  = xn1;
    u16t* k_t  = xn2;
    u16t* v_t  = a0n1;
    u16t* obf  = q_t;                      // in-place alias (fragment layout)
    u16t* wpk  = (u16t*)(ws + 75497472);

    dim3 blk(256);
    dim3 gprep(8, 64, 4);   // T/64, F, B
    dim3 gconv(8, 16, 4);   // T/64, F/4, B

    hipLaunchKernelGGL(prep_x3_k, gprep, blk, 0, stream, x,
        bd0_g, bd0_b, bd0_m, bd0_v, bd1_g, bd1_b, bd1_m, bd1_v,
        bdo_g, bdo_b, bdo_m, bdo_v, xn0, xn1, xn2);
    hipLaunchKernelGGL(prep_w_k, dim3(564), blk, 0, stream,
        bd0_w, bd1_w, bdo_w, o_w, sao_w, qkv_w, wpk);
    hipLaunchKernelGGL((conv3x3_ff4_k<64, 32, 2>), gconv, blk, 0, stream,
        xn0, nullptr, nullptr, wpk, bd0_wb,
        bd1_g, bd1_b, bd1_m, bd1_v, bdo_g, bdo_b, bdo_m, bdo_v,
        64, a0n1, a0n2);
    hipLaunchKernelGGL((conv3x3_ff4_k<96, 32, 1>), gconv, blk, 0, stream,
        xn1, a0n1, nullptr, wpk + 18432, bd1_wb,
        bdo_g, bdo_b, bdo_m, bdo_v, nullptr, nullptr, nullptr, nullptr,
        96, a1n2, nullptr);
    hipLaunchKernelGGL((conv3x3_ff4_k<128, 64, 0>), gconv, blk, 0, stream,
        xn2, a0n2, a1n2, wpk + 46080, bdo_wb,
        nullptr, nullptr, nullptr, nullptr, nullptr, nullptr, nullptr, nullptr,
        0, ybf, nullptr);
    hipLaunchKernelGGL(qkv_mfma_k, gprep, blk, 0, stream,
        ybf, wpk + 132096, qkv_b, q_t, k_t, v_t);
    hipLaunchKernelGGL(attn_mfma_k, dim3(32, 64, 4), blk, 0, stream,
        q_t, k_t, v_t, obf);
    hipLaunchKernelGGL(final_mfma_k, gprep, blk, 0, stream,
        obf, ybf, wpk + 119808, o_b, sao_g, sao_b, sao_m, sao_v,
        wpk + 123904, sao_wb, (float*)d_out);
}